// Round 1
// baseline (624.434 us; speedup 1.0000x reference)
//
#include <hip/hip_runtime.h>
#include <math.h>

// qkv: (B=4, S=4096, 3, H=16, D=128) fp32. RoPE on t=0 (q) and t=1 (k),
// pairing d with d+64, angle = (offset[b]+s) * 10000^(-d/64), d in [0,64).
// t=2 (v) is a straight copy. Output layout == input layout.
//
// V2: the 64 unique (cos,sin) pairs per block are computed ONCE by wave 0
// (1 sincosf/lane instead of 4 sincosf/thread = 16x less trig, and no
// divergent libm range-reduction in the main path), staged in LDS.
// Numerics identical to V1: same exp2f/sincosf calls, same inputs.

#define B_NUM 4
#define S_LEN 4096
#define H_NUM 16
#define D_DIM 128
#define HALF  64

// -log2(10000)/64
#define NEG_L2B_OVER_HALF (-0.2076205059304601f)

__global__ __launch_bounds__(256) void rope_kernel(
    const float4* __restrict__ in,
    const int* __restrict__ offsets,
    float4* __restrict__ out)
{
    const int bx  = blockIdx.x;          // bx = ((b*S + s)*3 + t)
    const int t   = bx % 3;
    const int bs  = bx / 3;              // b*S + s
    const int s   = bs & (S_LEN - 1);
    const int b   = bs >> 12;

    const int tid = threadIdx.x;
    const int c4  = tid & 15;            // float4 index within first half [0,16)
    const int h   = tid >> 4;            // head [0,16)

    // flat float4 index: ((bx*H + h) * D + 4*c4) / 4  — fits in 32 bits
    const int base = (bx * H_NUM + h) * (D_DIM / 4) + c4;

    __shared__ float2 cs[HALF];          // (cos, sin) for j = 0..63

    float4 x1 = in[base];                // dims [4*c4, 4*c4+4)
    float4 x2 = in[base + HALF / 4];     // dims [64+4*c4, 64+4*c4+4)

    if (t < 2) {
        // Wave 0 computes the 64 unique (cos,sin) pairs for this (b,s).
        // Overlaps with the global-load latency of waves 0-3.
        if (tid < HALF) {
            const float pos  = (float)(offsets[b] + s);
            const float invf = exp2f((float)tid * NEG_L2B_OVER_HALF);
            float sv, cv;
            sincosf(pos * invf, &sv, &cv);
            cs[tid] = make_float2(cv, sv);
        }
        __syncthreads();                 // t is block-uniform: barrier is safe

        float4 o1, o2;
        float* p1 = &o1.x; float* p2 = &o2.x;
        const float* q1 = &x1.x; const float* q2 = &x2.x;
        #pragma unroll
        for (int k = 0; k < 4; ++k) {
            const float2 p = cs[c4 * 4 + k];   // contiguous 32B/thread -> ds_read_b128 x2
            p1[k] = q1[k] * p.x - q2[k] * p.y;
            p2[k] = q1[k] * p.y + q2[k] * p.x;
        }
        x1 = o1;
        x2 = o2;
    }
    // t == 2: passthrough (v)

    out[base]            = x1;
    out[base + HALF / 4] = x2;
}

extern "C" void kernel_launch(void* const* d_in, const int* in_sizes, int n_in,
                              void* d_out, int out_size, void* d_ws, size_t ws_size,
                              hipStream_t stream)
{
    const float4* qkv = (const float4*)d_in[0];
    const int* offsets = (const int*)d_in[1];
    float4* outp = (float4*)d_out;

    const int grid = B_NUM * S_LEN * 3;   // 49152 blocks, one per (b,s,t)
    rope_kernel<<<grid, 256, 0, stream>>>(qkv, offsets, outp);
}